// Round 7
// baseline (323.311 us; speedup 1.0000x reference)
//
#include <hip/hip_runtime.h>
#include <hip/hip_bf16.h>

#define IMG 224
#define NPS 14
#define NP  196
#define BATCH 64
#define PD  3840
#define PROJ 768
#define M_TOT (BATCH*NP)        // 12544
#define TOK_SIZE (M_TOT*PROJ)   // 9633792
#define KT  120                 // PD/32
#define MT  98                  // M_TOT/128
#define NT  6                   // PROJ/128
#define TILE_BYTES 8192         // 128*32*2
#define IMG_BYTES 38535168      // 64*224*224*3*4
#define WBUF 15488              // per-wave LDS buffer (121*128)

typedef __attribute__((ext_vector_type(8))) __bf16 bf16x8;
typedef __attribute__((ext_vector_type(4))) float f32x4;

__device__ __forceinline__ unsigned short f2bf(float f) {
    unsigned int u = __builtin_bit_cast(unsigned int, f);
    u += 0x7FFFu + ((u >> 16) & 1u);
    return (unsigned short)(u >> 16);
}

// LDS bank-swizzle: XOR byte-addr bits[6:4] with bits[11:9] (stays in 128B block).
__device__ __forceinline__ int swz(int a) { return a ^ (((a >> 9) & 7) << 4); }

#define GLD16(gsrc, ldst) __builtin_amdgcn_global_load_lds( \
    (const __attribute__((address_space(1))) unsigned int*)(gsrc), \
    (__attribute__((address_space(3))) unsigned int*)(ldst), 16, 0, 0)

// ============== FAST PATH ==============

// prep5: wave-per-patch, ZERO barriers. Each wave: 15 float4 loads/lane ->
// scatter to wave-private LDS (d-layout, swizzled) -> lgkmcnt(0) ->
// pass1 (sums + coalesced patches f32 store) -> butterfly -> pass2 (LN -> Aws).
__global__ __launch_bounds__(256, 2) void prep5_kernel(
    const float* __restrict__ images, const float* __restrict__ gamma,
    const float* __restrict__ beta, float* __restrict__ patches_out,
    char* __restrict__ Aws) {
  __shared__ __align__(16) char pbuf[4][WBUF];
  const int t = threadIdx.x;
  const int l = t & 63;
  const int w = t >> 6;
  char* const wb = &pbuf[w][0];

  // ---- preamble: patch-independent per-lane address precompute ----
  int rel[15];                       // biased source byte offset
  int la0[15], la1[15], la2[15], la3[15];   // swizzled LDS scatter byte addrs
  unsigned msk[15];                  // iof8(5b) | 4x joff(6b at 8,14,20,26)
  #pragma unroll
  for (int it = 0; it < 15; ++it) {
    int f = l + 64*it;               // source float4 index 0..959
    int run = f / 12, slot = f - run*12;
    int g = run >> 4, p = run & 15;
    int dh = (g==0) ? 0 : ((g & 1) ? 8 : -8);
    int dw = (g==0) ? 0 : ((g <= 2) ? 8 : -8);
    rel[it] = ((p+dh)*224 + dw)*12 + slot*16 + 32768;
    int s0 = slot*4;
    int q0 = s0/3, c0 = s0 - q0*3;
    int dbase = (p*16 + q0)*15 + g*3 + c0;
    int dd1 = (c0==2) ? 13 : 1;
    int dd2 = (c0==0) ? 2 : 14;
    la0[it] = swz(4*dbase);
    la1[it] = swz(4*(dbase+dd1));
    la2[it] = swz(4*(dbase+dd2));
    la3[it] = swz(4*(dbase+15));
    unsigned m = (unsigned)(p + dh + 8);       // iof8, 5 bits
    #pragma unroll
    for (int k = 0; k < 4; ++k) {
      int qk = q0 + ((c0 + k) >= 3 ? 1 : 0);
      m |= (unsigned)(dw + qk + 8) << (8 + 6*k);
    }
    msk[it] = m;
  }

  const int wgid = blockIdx.x*4 + w;

  for (int j = 0; j < 4; ++j) {
    const int pid = wgid*4 + j;
    const int b  = pid / NP;
    const int pp = pid - b*NP;
    const int ph = pp / NPS;
    const int pw = pp - ph*NPS;
    const int pixoff = (b*50176 + (ph*224 + pw)*16)*12;
    const char* sbase = (const char*)images + (pixoff - 32768);

    // ---- phase a: load + LDS scatter (wave-private, no sync needed) ----
    if (ph != 0 && ph != 13 && pw != 0 && pw != 13) {
      #pragma unroll
      for (int it = 0; it < 15; ++it) {
        float4 v4 = *(const float4*)(sbase + rel[it]);
        *(float*)(wb + la0[it]) = v4.x;
        *(float*)(wb + la1[it]) = v4.y;
        *(float*)(wb + la2[it]) = v4.z;
        *(float*)(wb + la3[it]) = v4.w;
      }
    } else {
      int ph16 = ph*16 - 8, pw16 = pw*16 - 8;
      int lo = 32768 - pixoff;
      int hi = IMG_BYTES - pixoff + 32768 - 16;
      #pragma unroll
      for (int it = 0; it < 15; ++it) {
        int ii = ph16 + (int)(msk[it] & 31u);
        bool rowok = (unsigned)ii < 224u;
        int vo = rowok ? rel[it] : 32768;
        vo = vo < lo ? lo : vo;
        vo = vo > hi ? hi : vo;
        float4 v4 = *(const float4*)(sbase + vo);
        int j0 = pw16 + (int)((msk[it] >> 8)  & 63u);
        int j1 = pw16 + (int)((msk[it] >> 14) & 63u);
        int j2 = pw16 + (int)((msk[it] >> 20) & 63u);
        int j3 = pw16 + (int)((msk[it] >> 26) & 63u);
        *(float*)(wb + la0[it]) = (rowok && (unsigned)j0 < 224u) ? v4.x : 0.f;
        *(float*)(wb + la1[it]) = (rowok && (unsigned)j1 < 224u) ? v4.y : 0.f;
        *(float*)(wb + la2[it]) = (rowok && (unsigned)j2 < 224u) ? v4.z : 0.f;
        *(float*)(wb + la3[it]) = (rowok && (unsigned)j3 < 224u) ? v4.w : 0.f;
      }
    }
    asm volatile("s_waitcnt lgkmcnt(0)" ::: "memory");
    __builtin_amdgcn_sched_barrier(0);

    // ---- pass 1: sums + coalesced patches f32 store ----
    float s = 0.f, q = 0.f;
    float* po = patches_out + (size_t)pid*PD;
    #pragma unroll
    for (int r = 0; r < 15; ++r) {
      f32x4 v = *(const f32x4*)(wb + swz(r*1024 + l*16));
      *(f32x4*)(po + 4*l + 256*r) = v;
      s += (v[0] + v[1]) + (v[2] + v[3]);
      q += (v[0]*v[0] + v[1]*v[1]) + (v[2]*v[2] + v[3]*v[3]);
    }
    #pragma unroll
    for (int o = 32; o > 0; o >>= 1) { s += __shfl_xor(s, o); q += __shfl_xor(q, o); }
    const float mean = s * (1.f/PD);
    const float rstd = rsqrtf(q*(1.f/PD) - mean*mean + 1e-6f);

    // ---- pass 2: LN + Aws bf16 store (re-read LDS to cap VGPRs) ----
    const int mtile = pid >> 7, mrow = pid & 127;
    // full-sum-then-XOR (matches gemm read side)
    const int arow = (mrow*64 + 8*(l & 7)) ^ ((mrow & 7) << 4);
    char* abase = Aws + ((size_t)(mtile*KT + (l >> 3)))*TILE_BYTES + arow;
    #pragma unroll
    for (int r = 0; r < 15; ++r) {
      f32x4 v = *(const f32x4*)(wb + swz(r*1024 + l*16));
      int f4 = 4*l + 256*r;
      float4 gv = *(const float4*)(gamma + f4);
      float4 bv = *(const float4*)(beta + f4);
      float f0 = fmaf(v[0] - mean, rstd*gv.x, bv.x);
      float f1 = fmaf(v[1] - mean, rstd*gv.y, bv.y);
      float f2 = fmaf(v[2] - mean, rstd*gv.z, bv.z);
      float f3 = fmaf(v[3] - mean, rstd*gv.w, bv.w);
      unsigned u0, u1;
      asm("v_cvt_pk_bf16_f32 %0, %1, %2" : "=v"(u0) : "v"(f0), "v"(f1));
      asm("v_cvt_pk_bf16_f32 %0, %1, %2" : "=v"(u1) : "v"(f2), "v"(f3));
      *(uint2*)(abase + (size_t)r*8*TILE_BYTES) = make_uint2(u0, u1);
    }
  }
}

// wtrans2: W (3840x768 f32) -> tiled+swizzled bf16 [ntile][ktile][128x32]
__global__ __launch_bounds__(256) void wtrans2_kernel(
    const float* __restrict__ W, char* __restrict__ Bws) {
  __shared__ float tile[32][33];
  const int bx = blockIdx.x;
  const int by = blockIdx.y;
  const int tid = threadIdx.x;
  const int nl = tid & 31;
  #pragma unroll
  for (int r = 0; r < 4; ++r) {
    int kl = (tid >> 5) + r*8;
    tile[nl][kl] = W[(by*32 + kl)*PROJ + bx*32 + nl];
  }
  __syncthreads();
  if (tid < 128) {
    const int n_local = tid >> 2;
    const int kchunk  = tid & 3;
    unsigned int u[4];
    #pragma unroll
    for (int j = 0; j < 4; ++j) {
      unsigned short lo = f2bf(tile[n_local][kchunk*8 + j*2]);
      unsigned short hi = f2bf(tile[n_local][kchunk*8 + j*2 + 1]);
      u[j] = (unsigned)lo | ((unsigned)hi << 16);
    }
    const int n = bx*32 + n_local;
    const int ntile = n >> 7, nrow = n & 127;
    const int kk8 = kchunk * 8;
    const int byteoff = (nrow*64 + kk8*2) ^ ((nrow & 7) << 4);
    *(uint4*)(Bws + ((size_t)(ntile*KT + by))*TILE_BYTES + byteoff) =
        make_uint4(u[0], u[1], u[2], u[3]);
  }
}

// gemm4: counted-vmcnt 3-buffer ring + XCD-colocated block mapping (unchanged).
__global__ __launch_bounds__(256) void gemm4_kernel(
    const char* __restrict__ Aws, const char* __restrict__ Bws,
    const float* __restrict__ bias, float* __restrict__ tokens) {
  __shared__ __align__(16) char lds3[3][2*TILE_BYTES];   // 48 KB
  const int bid = blockIdx.x;
  const int xcd = bid & 7, pos = bid >> 3;
  const int virt = (xcd < 4) ? xcd*74 + pos : 296 + (xcd - 4)*73 + pos;
  const int bm = virt / 6;
  const int bn = virt - bm*6;

  const int t = threadIdx.x;
  const int l = t & 63;
  const int w = t >> 6;
  const int wr = w >> 1, wc = w & 1;
  const int lrow = l & 15;
  const int lk   = l >> 4;

  const char* Ag = Aws + (size_t)bm*KT*TILE_BYTES;
  const char* Bg = Bws + (size_t)bn*KT*TILE_BYTES;
  const int ga0 = (2*w + 0)*1024 + l*16;
  const int ga1 = (2*w + 1)*1024 + l*16;
  const int da0 = (2*w + 0)*1024;
  const int da1 = (2*w + 1)*1024;

  int aoff[4], boff[4];
  #pragma unroll
  for (int fr = 0; fr < 4; ++fr) {
    int row = wr*64 + fr*16 + lrow;
    aoff[fr] = (row*64 + lk*16) ^ ((row & 7) << 4);
  }
  #pragma unroll
  for (int fc = 0; fc < 4; ++fc) {
    int row = wc*64 + fc*16 + lrow;
    boff[fc] = TILE_BYTES + ((row*64 + lk*16) ^ ((row & 7) << 4));
  }

  f32x4 acc[4][4];
  #pragma unroll
  for (int i = 0; i < 4; ++i)
    #pragma unroll
    for (int j = 0; j < 4; ++j) acc[i][j] = f32x4{0.f, 0.f, 0.f, 0.f};

  auto STAGE = [&](int kt, char* base) {
    const size_t off = (size_t)kt * TILE_BYTES;
    GLD16(Ag + off + ga0, base + da0);
    GLD16(Ag + off + ga1, base + da1);
    GLD16(Bg + off + ga0, base + TILE_BYTES + da0);
    GLD16(Bg + off + ga1, base + TILE_BYTES + da1);
  };

  char* curb  = &lds3[0][0];
  char* nextb = &lds3[1][0];
  char* spare = &lds3[2][0];
  STAGE(0, curb);
  STAGE(1, nextb);

  for (int kt = 0; kt < KT; ++kt) {
    if (kt < KT - 1) asm volatile("s_waitcnt vmcnt(4)" ::: "memory");
    else             asm volatile("s_waitcnt vmcnt(0)" ::: "memory");
    __builtin_amdgcn_s_barrier();
    __builtin_amdgcn_sched_barrier(0);
    if (kt + 2 < KT) STAGE(kt + 2, spare);
    bf16x8 af[4], bf[4];
    #pragma unroll
    for (int fr = 0; fr < 4; ++fr) af[fr] = *(const bf16x8*)(curb + aoff[fr]);
    #pragma unroll
    for (int fc = 0; fc < 4; ++fc) bf[fc] = *(const bf16x8*)(curb + boff[fc]);
    #pragma unroll
    for (int fr = 0; fr < 4; ++fr)
      #pragma unroll
      for (int fc = 0; fc < 4; ++fc)
        acc[fr][fc] = __builtin_amdgcn_mfma_f32_16x16x32_bf16(
            af[fr], bf[fc], acc[fr][fc], 0, 0, 0);
    char* tmp = curb; curb = nextb; nextb = spare; spare = tmp;
  }

  const int m0 = bm * 128, n0 = bn * 128;
  #pragma unroll
  for (int fr = 0; fr < 4; ++fr) {
    int mrow = m0 + wr*64 + fr*16 + lk*4;
    #pragma unroll
    for (int fc = 0; fc < 4; ++fc) {
      int col = n0 + wc*64 + fc*16 + lrow;
      float bb = bias[col];
      #pragma unroll
      for (int i = 0; i < 4; ++i)
        tokens[(size_t)(mrow + i)*PROJ + col] = acc[fr][fc][i] + bb;
    }
  }
}

// ============== FALLBACK PATH (round-1, known-passing) ==============

__global__ __launch_bounds__(256) void prep_kernel(
    const float* __restrict__ images, float* __restrict__ patches_out,
    float2* __restrict__ mr) {
  const int pid = blockIdx.x;
  const int b  = pid / NP;
  const int pp = pid - b*NP;
  const int ph = pp / NPS;
  const int pw = pp - ph*NPS;
  const int t = threadIdx.x;
  float s = 0.f, s2 = 0.f;
  #pragma unroll
  for (int r = 0; r < 15; ++r) {
    int d   = t + r*256;
    int ch5 = d % 15;
    int rem = d / 15;
    int q = rem & 15;
    int p = rem >> 4;
    int g = ch5 / 3;
    int c = ch5 - g*3;
    int dh = (g==0) ? 0 : ((g & 1) ? 8 : -8);
    int dw = (g==0) ? 0 : ((g <= 2) ? 8 : -8);
    int ii = ph*16 + p + dh;
    int jj = pw*16 + q + dw;
    float v = 0.f;
    if ((unsigned)ii < IMG && (unsigned)jj < IMG)
      v = images[((b*IMG + ii)*IMG + jj)*3 + c];
    s += v; s2 += v*v;
    patches_out[(size_t)pid*PD + d] = v;
  }
  #pragma unroll
  for (int o = 32; o > 0; o >>= 1) { s += __shfl_xor(s, o); s2 += __shfl_xor(s2, o); }
  __shared__ float red[8];
  int w = t >> 6;
  if ((t & 63) == 0) { red[w*2] = s; red[w*2+1] = s2; }
  __syncthreads();
  if (t == 0) {
    float S  = red[0]+red[2]+red[4]+red[6];
    float S2 = red[1]+red[3]+red[5]+red[7];
    float mean = S * (1.f/PD);
    float var  = S2 * (1.f/PD) - mean*mean;
    mr[pid] = make_float2(mean, rsqrtf(var + 1e-6f));
  }
}

__global__ __launch_bounds__(256) void wtrans_kernel(
    const float* __restrict__ W, unsigned short* __restrict__ Wt) {
  __shared__ float tile[32][33];
  const int bx = blockIdx.x;
  const int by = blockIdx.y;
  const int tx = threadIdx.x & 31;
  const int ty = threadIdx.x >> 5;
  #pragma unroll
  for (int r = 0; r < 4; ++r)
    tile[ty + r*8][tx] = W[(by*32 + ty + r*8)*PROJ + bx*32 + tx];
  __syncthreads();
  #pragma unroll
  for (int r = 0; r < 4; ++r)
    Wt[(size_t)(bx*32 + ty + r*8)*PD + by*32 + tx] = f2bf(tile[tx][ty + r*8]);
}

__global__ __launch_bounds__(256) void gemm_kernel(
    const float* __restrict__ patches, const float2* __restrict__ mr,
    const float* __restrict__ gamma, const float* __restrict__ beta,
    const unsigned short* __restrict__ Wt, const float* __restrict__ bias,
    float* __restrict__ tokens) {
  __shared__ unsigned short Alds[128][40];
  const int bn = blockIdx.x;
  const int bm = blockIdx.y;
  const int t = threadIdx.x;
  const int l = t & 63;
  const int w = t >> 6;
  const int wr = w >> 1, wc = w & 1;
  const int m0 = bm * 128, n0 = bn * 128;
  const int lrow = l & 15, lk = l >> 4;
  const unsigned short* bp[4];
  #pragma unroll
  for (int fc = 0; fc < 4; ++fc)
    bp[fc] = Wt + (size_t)(n0 + wc*64 + fc*16 + lrow) * PD + lk*8;
  const int srow = t >> 3;
  const int skq  = (t & 7) * 4;
  f32x4 acc[4][4];
  #pragma unroll
  for (int i = 0; i < 4; ++i)
    #pragma unroll
    for (int j = 0; j < 4; ++j) acc[i][j] = f32x4{0.f, 0.f, 0.f, 0.f};
  bf16x8 bfrag[4], bnext[4];
  #pragma unroll
  for (int fc = 0; fc < 4; ++fc) bfrag[fc] = *reinterpret_cast<const bf16x8*>(bp[fc]);
  for (int kt = 0; kt < KT; ++kt) {
    const int k0 = kt * 32;
    #pragma unroll
    for (int pass = 0; pass < 4; ++pass) {
      int row = pass*32 + srow;
      int m = m0 + row;
      float2 mrv = mr[m];
      const float4 v  = *reinterpret_cast<const float4*>(patches + (size_t)m*PD + k0 + skq);
      const float4 gv = *reinterpret_cast<const float4*>(gamma + k0 + skq);
      const float4 bv = *reinterpret_cast<const float4*>(beta  + k0 + skq);
      ushort4 o;
      o.x = f2bf((v.x - mrv.x)*mrv.y*gv.x + bv.x);
      o.y = f2bf((v.y - mrv.x)*mrv.y*gv.y + bv.y);
      o.z = f2bf((v.z - mrv.x)*mrv.y*gv.z + bv.z);
      o.w = f2bf((v.w - mrv.x)*mrv.y*gv.w + bv.w);
      *reinterpret_cast<ushort4*>(&Alds[row][skq]) = o;
    }
    if (kt < KT-1) {
      #pragma unroll
      for (int fc = 0; fc < 4; ++fc)
        bnext[fc] = *reinterpret_cast<const bf16x8*>(bp[fc] + k0 + 32);
    }
    __syncthreads();
    bf16x8 afrag[4];
    #pragma unroll
    for (int fr = 0; fr < 4; ++fr)
      afrag[fr] = *reinterpret_cast<const bf16x8*>(&Alds[wr*64 + fr*16 + lrow][lk*8]);
    #pragma unroll
    for (int fr = 0; fr < 4; ++fr)
      #pragma unroll
      for (int fc = 0; fc < 4; ++fc)
        acc[fr][fc] = __builtin_amdgcn_mfma_f32_16x16x32_bf16(
            afrag[fr], bfrag[fc], acc[fr][fc], 0, 0, 0);
    __syncthreads();
    #pragma unroll
    for (int fc = 0; fc < 4; ++fc) bfrag[fc] = bnext[fc];
  }
  #pragma unroll
  for (int fr = 0; fr < 4; ++fr) {
    int mrow = m0 + wr*64 + fr*16 + lk*4;
    #pragma unroll
    for (int fc = 0; fc < 4; ++fc) {
      int col = n0 + wc*64 + fc*16 + lrow;
      float bb = bias[col];
      #pragma unroll
      for (int i = 0; i < 4; ++i)
        tokens[(size_t)(mrow + i)*PROJ + col] = acc[fr][fc][i] + bb;
    }
  }
}

// ============== launcher ==============

extern "C" void kernel_launch(void* const* d_in, const int* in_sizes, int n_in,
                              void* d_out, int out_size, void* d_ws, size_t ws_size,
                              hipStream_t stream) {
  const float* images = (const float*)d_in[0];
  const float* gamma  = (const float*)d_in[1];
  const float* beta   = (const float*)d_in[2];
  const float* W      = (const float*)d_in[3];
  const float* bias   = (const float*)d_in[4];
  float* tokens  = (float*)d_out;
  float* patches = (float*)d_out + TOK_SIZE;

  const size_t WS_A_OFF = 6u << 20;                               // 6 MiB
  const size_t need = WS_A_OFF + (size_t)MT*KT*TILE_BYTES;        // ~98 MiB

  if (ws_size >= need) {
    char* Bws = (char*)d_ws;
    char* Aws = (char*)d_ws + WS_A_OFF;
    prep5_kernel<<<784, 256, 0, stream>>>(images, gamma, beta, patches, Aws);
    wtrans2_kernel<<<dim3(24, KT), 256, 0, stream>>>(W, Bws);
    gemm4_kernel<<<MT*NT, 256, 0, stream>>>(Aws, Bws, bias, tokens);
  } else {
    float2* mrp = (float2*)d_ws;
    unsigned short* Wt = (unsigned short*)((char*)d_ws + (1 << 20));
    prep_kernel<<<M_TOT, 256, 0, stream>>>(images, patches, mrp);
    wtrans_kernel<<<dim3(24, KT), 256, 0, stream>>>(W, Wt);
    gemm_kernel<<<dim3(NT, MT), 256, 0, stream>>>(patches, mrp, gamma, beta, Wt, bias, tokens);
  }
}

// Round 8
// 190.660 us; speedup vs baseline: 1.6957x; 1.6957x over previous
//
#include <hip/hip_runtime.h>
#include <hip/hip_bf16.h>

#define IMG 224
#define NPS 14
#define NP  196
#define BATCH 64
#define PD  3840
#define PROJ 768
#define M_TOT (BATCH*NP)        // 12544
#define TOK_SIZE (M_TOT*PROJ)   // 9633792
#define KT  120                 // PD/32
#define MT  98                  // M_TOT/128
#define NT  6                   // PROJ/128
#define TILE_BYTES 8192         // 128*32*2
#define IMG_BYTES 38535168      // 64*224*224*3*4

typedef __attribute__((ext_vector_type(8))) __bf16 bf16x8;
typedef __attribute__((ext_vector_type(4))) float f32x4;

__device__ __forceinline__ unsigned short f2bf(float f) {
    unsigned int u = __builtin_bit_cast(unsigned int, f);
    u += 0x7FFFu + ((u >> 16) & 1u);
    return (unsigned short)(u >> 16);
}

// pbuf bank-swizzle: XOR byte-addr bits[6:4] with bits[11:9].
__device__ __forceinline__ int swz(int a) { return a ^ (((a >> 9) & 7) << 4); }

#define GLD16(gsrc, ldst) __builtin_amdgcn_global_load_lds( \
    (const __attribute__((address_space(1))) unsigned int*)(gsrc), \
    (__attribute__((address_space(3))) unsigned int*)(ldst), 16, 0, 0)

// ============== FAST PATH ==============

// prep4: grid-stride pipelined gather + LN (round-6 version + nontemporal
// patches stores to keep image/Aws resident in L3).
__global__ __launch_bounds__(512, 4) void prep4_kernel(
    const float* __restrict__ images, const float* __restrict__ gamma,
    const float* __restrict__ beta, float* __restrict__ patches_out,
    char* __restrict__ Aws) {
  __shared__ float pbuf[2][4096];
  __shared__ __align__(16) float red_s[2][8];
  __shared__ __align__(16) float red_q[2][8];
  const int t = threadIdx.x;
  char* const pb = (char*)&pbuf[0][0];

  int relv[2];
  int la[2][4];
  int iof8[2];
  unsigned jpk[2];
  #pragma unroll
  for (int u = 0; u < 2; ++u) {
    int uu = t + u*512;
    if (uu < 960) {
      int run = uu / 12, slot = uu - run*12;
      int g = run >> 4, p = run & 15;
      int dh = (g==0) ? 0 : ((g & 1) ? 8 : -8);
      int dw = (g==0) ? 0 : ((g <= 2) ? 8 : -8);
      int ioff = p + dh;
      relv[u] = ((ioff*224 + dw)*3 + slot*4)*4 + 32768;
      iof8[u] = ioff + 8;
      int i48 = slot*4;
      int q0 = i48/3, c0 = i48 - q0*3;
      int dbase = (p*16 + q0)*15 + g*3 + c0;
      int dd1 = (c0==2) ? 13 : 1;
      int dd2 = (c0==0) ? 2 : 14;
      la[u][0] = swz(dbase*4);
      la[u][1] = swz((dbase+dd1)*4);
      la[u][2] = swz((dbase+dd2)*4);
      la[u][3] = swz((dbase+15)*4);
      unsigned jp = 0;
      #pragma unroll
      for (int k = 0; k < 4; ++k) {
        int qk = q0 + ((c0 + k) >= 3 ? 1 : 0);
        jp |= (unsigned)(dw + qk + 8) << (8*k);
      }
      jpk[u] = jp;
    } else {
      relv[u] = 32768; iof8[u] = 0; jpk[u] = 0;
      la[u][0] = swz(4000*4); la[u][1] = swz(4001*4);
      la[u][2] = swz(4002*4); la[u][3] = swz(4003*4);
    }
  }

  const int d0 = (t < 480) ? t*8 : 0;
  const int rba = swz(d0*4);
  const int rbb = swz(d0*4 + 16);
  const int voffA = (t >> 2)*8192 + (t & 3)*16;
  float4 g8a = *(const float4*)(gamma + d0);
  float4 g8b = *(const float4*)(gamma + d0 + 4);
  float4 b8a = *(const float4*)(beta + d0);
  float4 b8b = *(const float4*)(beta + d0 + 4);

  auto do_loads = [&](int np, int toggle) -> float2 {
    int b  = np / NP;
    int pp = np - b*NP;
    int ph = pp / NPS;
    int pw = pp - ph*NPS;
    int pixoff = (b*50176 + (ph*224 + pw)*16)*12;
    const char* sbase = (const char*)images + (pixoff - 32768);
    float s = 0.f, q = 0.f;
    char* lb = pb + toggle;
    if (ph != 0 && ph != 13 && pw != 0 && pw != 13) {
      #pragma unroll
      for (int u = 0; u < 2; ++u) {
        if (u == 0 || t < 448) {
          float4 v4 = *(const float4*)(sbase + relv[u]);
          s += (v4.x + v4.y) + (v4.z + v4.w);
          q += (v4.x*v4.x + v4.y*v4.y) + (v4.z*v4.z + v4.w*v4.w);
          *(float*)(lb + la[u][0]) = v4.x;
          *(float*)(lb + la[u][1]) = v4.y;
          *(float*)(lb + la[u][2]) = v4.z;
          *(float*)(lb + la[u][3]) = v4.w;
        }
      }
    } else {
      int ph16 = ph*16 - 8, pw16 = pw*16 - 8;
      int lo = 32768 - pixoff;
      int hi = IMG_BYTES - pixoff + 32768 - 16;
      #pragma unroll
      for (int u = 0; u < 2; ++u) {
        if (u == 0 || t < 448) {
          int ii = ph16 + iof8[u];
          bool rowok = (unsigned)ii < 224u;
          int vo = rowok ? relv[u] : 32768;
          vo = vo < lo ? lo : vo;
          vo = vo > hi ? hi : vo;
          float4 v4 = *(const float4*)(sbase + vo);
          float vv0 = v4.x, vv1 = v4.y, vv2 = v4.z, vv3 = v4.w;
          #pragma unroll
          for (int k = 0; k < 4; ++k) {
            int jj = pw16 + (int)((jpk[u] >> (8*k)) & 255u);
            float x = (k==0?vv0:(k==1?vv1:(k==2?vv2:vv3)));
            x = (rowok && (unsigned)jj < 224u) ? x : 0.f;
            s += x; q += x*x;
            *(float*)(lb + la[u][k]) = x;
          }
        }
      }
    }
    return make_float2(s, q);
  };

  const int bi = blockIdx.x;
  const int start = bi*12 + (bi < 256 ? bi : 256);
  const int cnt = (bi < 256) ? 13 : 12;

  float2 curps = do_loads(start, 0);
  __syncthreads();
  int cur = 0;

  for (int j = 0; j < cnt; ++j) {
    const int p_ = start + j;
    float4 va = *(const float4*)(pb + (cur << 14) + rba);
    float4 vb = *(const float4*)(pb + (cur << 14) + rbb);
    float s = curps.x, q = curps.y;
    #pragma unroll
    for (int o = 32; o > 0; o >>= 1) { s += __shfl_xor(s, o); q += __shfl_xor(q, o); }
    if ((t & 63) == 0) { red_s[cur][t >> 6] = s; red_q[cur][t >> 6] = q; }
    float2 nps = make_float2(0.f, 0.f);
    if (j + 1 < cnt) nps = do_loads(p_ + 1, (cur ^ 1) << 14);
    __syncthreads();
    {
      const float* rs = red_s[cur]; const float* rq = red_q[cur];
      float4 sa = *(const float4*)rs;  float4 sb = *(const float4*)(rs + 4);
      float4 qa = *(const float4*)rq;  float4 qb = *(const float4*)(rq + 4);
      float S = ((sa.x+sa.y)+(sa.z+sa.w)) + ((sb.x+sb.y)+(sb.z+sb.w));
      float Q = ((qa.x+qa.y)+(qa.z+qa.w)) + ((qb.x+qb.y)+(qb.z+qb.w));
      float mean = S * (1.f/PD);
      float rstd = rsqrtf(Q*(1.f/PD) - mean*mean + 1e-6f);
      if (t < 480) {
        float* po = patches_out + (size_t)p_*PD + d0;
        // non-temporal: patches is never re-read — don't pollute L2/L3
        f32x4 vva = __builtin_bit_cast(f32x4, va);
        f32x4 vvb = __builtin_bit_cast(f32x4, vb);
        __builtin_nontemporal_store(vva, (f32x4*)po);
        __builtin_nontemporal_store(vvb, (f32x4*)(po + 4));
        float f0 = fmaf(va.x - mean, rstd*g8a.x, b8a.x);
        float f1 = fmaf(va.y - mean, rstd*g8a.y, b8a.y);
        float f2 = fmaf(va.z - mean, rstd*g8a.z, b8a.z);
        float f3 = fmaf(va.w - mean, rstd*g8a.w, b8a.w);
        float f4 = fmaf(vb.x - mean, rstd*g8b.x, b8b.x);
        float f5 = fmaf(vb.y - mean, rstd*g8b.y, b8b.y);
        float f6 = fmaf(vb.z - mean, rstd*g8b.z, b8b.z);
        float f7 = fmaf(vb.w - mean, rstd*g8b.w, b8b.w);
        unsigned u0, u1, u2, u3;
        asm("v_cvt_pk_bf16_f32 %0, %1, %2" : "=v"(u0) : "v"(f0), "v"(f1));
        asm("v_cvt_pk_bf16_f32 %0, %1, %2" : "=v"(u1) : "v"(f2), "v"(f3));
        asm("v_cvt_pk_bf16_f32 %0, %1, %2" : "=v"(u2) : "v"(f4), "v"(f5));
        asm("v_cvt_pk_bf16_f32 %0, %1, %2" : "=v"(u3) : "v"(f6), "v"(f7));
        int mrow = p_ & 127;
        int ub = (p_ >> 7)*(KT*TILE_BYTES) + ((mrow*64) ^ ((mrow & 4) << 4));
        *(uint4*)(Aws + (size_t)ub + (voffA ^ ((mrow & 3) << 4))) =
            make_uint4(u0, u1, u2, u3);
      }
    }
    curps = nps; cur ^= 1;
  }
}

// wtrans2: W (3840x768 f32) -> tiled+swizzled bf16 [ntile][ktile][128x32]
__global__ __launch_bounds__(256) void wtrans2_kernel(
    const float* __restrict__ W, char* __restrict__ Bws) {
  __shared__ float tile[32][33];
  const int bx = blockIdx.x;
  const int by = blockIdx.y;
  const int tid = threadIdx.x;
  const int nl = tid & 31;
  #pragma unroll
  for (int r = 0; r < 4; ++r) {
    int kl = (tid >> 5) + r*8;
    tile[nl][kl] = W[(by*32 + kl)*PROJ + bx*32 + nl];
  }
  __syncthreads();
  if (tid < 128) {
    const int n_local = tid >> 2;
    const int kchunk  = tid & 3;
    unsigned int u[4];
    #pragma unroll
    for (int j = 0; j < 4; ++j) {
      unsigned short lo = f2bf(tile[n_local][kchunk*8 + j*2]);
      unsigned short hi = f2bf(tile[n_local][kchunk*8 + j*2 + 1]);
      u[j] = (unsigned)lo | ((unsigned)hi << 16);
    }
    const int n = bx*32 + n_local;
    const int ntile = n >> 7, nrow = n & 127;
    const int kk8 = kchunk * 8;
    const int byteoff = (nrow*64 + kk8*2) ^ ((nrow & 7) << 4);
    *(uint4*)(Bws + ((size_t)(ntile*KT + by))*TILE_BYTES + byteoff) =
        make_uint4(u[0], u[1], u[2], u[3]);
  }
}

// gemm5: A-only LDS staging (ring-3, counted vmcnt), B register-direct from
// L2 with 1-tile prefetch, XCD-colocated mapping, nontemporal tokens store.
// Per-iter VMEM issue order (pinned): [breg(kt+1) x4][A_lds(kt+2) x2]; at the
// top of iter kt the wait vmcnt(2) retires breg(kt)+A(kt), leaves A(kt+1).
__global__ __launch_bounds__(256) void gemm5_kernel(
    const char* __restrict__ Aws, const char* __restrict__ Bws,
    const float* __restrict__ bias, float* __restrict__ tokens) {
  __shared__ __align__(16) char lds3[3][TILE_BYTES];   // 24 KB, A only
  const int bid = blockIdx.x;
  const int xcd = bid & 7, pos = bid >> 3;
  const int virt = (xcd < 4) ? xcd*74 + pos : 296 + (xcd - 4)*73 + pos;
  const int bm = virt / 6;
  const int bn = virt - bm*6;

  const int t = threadIdx.x;
  const int l = t & 63;
  const int w = t >> 6;
  const int wr = w >> 1, wc = w & 1;
  const int lrow = l & 15;
  const int lk   = l >> 4;

  const char* Ag = Aws + (size_t)bm*KT*TILE_BYTES;
  const char* Bg = Bws + (size_t)bn*KT*TILE_BYTES;
  const int ga0 = w*1024 + l*16;           // A slice, first 4KB
  const int ga1 = 4096 + w*1024 + l*16;    // A slice, second 4KB
  const int da0 = w*1024;
  const int da1 = 4096 + w*1024;

  int aoff[4], bloc[4];
  #pragma unroll
  for (int fr = 0; fr < 4; ++fr) {
    int row = wr*64 + fr*16 + lrow;
    aoff[fr] = (row*64 + lk*16) ^ ((row & 7) << 4);
  }
  #pragma unroll
  for (int fc = 0; fc < 4; ++fc) {
    int row = wc*64 + fc*16 + lrow;
    bloc[fc] = (row*64 + lk*16) ^ ((row & 7) << 4);
  }

  f32x4 acc[4][4];
  #pragma unroll
  for (int i = 0; i < 4; ++i)
    #pragma unroll
    for (int j = 0; j < 4; ++j) acc[i][j] = f32x4{0.f, 0.f, 0.f, 0.f};

  auto STAGE_A = [&](int kt, char* base) {
    const size_t off = (size_t)kt * TILE_BYTES;
    GLD16(Ag + off + ga0, base + da0);
    GLD16(Ag + off + ga1, base + da1);
  };

  char* curb  = &lds3[0][0];
  char* nextb = &lds3[1][0];
  char* spare = &lds3[2][0];

  // prologue: breg(0) FIRST, then A(0), A(1) -> uniform vmcnt(2) works at kt=0
  bf16x8 bf[4];
  #pragma unroll
  for (int fc = 0; fc < 4; ++fc) bf[fc] = *(const bf16x8*)(Bg + bloc[fc]);
  __builtin_amdgcn_sched_barrier(0);
  STAGE_A(0, curb);
  STAGE_A(1, nextb);

  for (int kt = 0; kt < KT; ++kt) {
    if (kt < KT - 1) asm volatile("s_waitcnt vmcnt(2)" ::: "memory");
    else             asm volatile("s_waitcnt vmcnt(0)" ::: "memory");
    __builtin_amdgcn_s_barrier();
    __builtin_amdgcn_sched_barrier(0);
    bf16x8 af[4];
    #pragma unroll
    for (int fr = 0; fr < 4; ++fr) af[fr] = *(const bf16x8*)(curb + aoff[fr]);
    #pragma unroll
    for (int fr = 0; fr < 4; ++fr)
      #pragma unroll
      for (int fc = 0; fc < 4; ++fc)
        acc[fr][fc] = __builtin_amdgcn_mfma_f32_16x16x32_bf16(
            af[fr], bf[fc], acc[fr][fc], 0, 0, 0);
    if (kt + 1 < KT) {
      const char* bsrc = Bg + (size_t)(kt + 1)*TILE_BYTES;
      #pragma unroll
      for (int fc = 0; fc < 4; ++fc) bf[fc] = *(const bf16x8*)(bsrc + bloc[fc]);
    }
    __builtin_amdgcn_sched_barrier(0);
    if (kt + 2 < KT) STAGE_A(kt + 2, spare);
    char* tmp = curb; curb = nextb; nextb = spare; spare = tmp;
  }

  const int m0 = bm * 128, n0 = bn * 128;
  #pragma unroll
  for (int fr = 0; fr < 4; ++fr) {
    int mrow = m0 + wr*64 + fr*16 + lk*4;
    #pragma unroll
    for (int fc = 0; fc < 4; ++fc) {
      int col = n0 + wc*64 + fc*16 + lrow;
      float bb = bias[col];
      #pragma unroll
      for (int i = 0; i < 4; ++i)
        __builtin_nontemporal_store(acc[fr][fc][i] + bb,
                                    &tokens[(size_t)(mrow + i)*PROJ + col]);
    }
  }
}

// ============== FALLBACK PATH (round-1, known-passing) ==============

__global__ __launch_bounds__(256) void prep_kernel(
    const float* __restrict__ images, float* __restrict__ patches_out,
    float2* __restrict__ mr) {
  const int pid = blockIdx.x;
  const int b  = pid / NP;
  const int pp = pid - b*NP;
  const int ph = pp / NPS;
  const int pw = pp - ph*NPS;
  const int t = threadIdx.x;
  float s = 0.f, s2 = 0.f;
  #pragma unroll
  for (int r = 0; r < 15; ++r) {
    int d   = t + r*256;
    int ch5 = d % 15;
    int rem = d / 15;
    int q = rem & 15;
    int p = rem >> 4;
    int g = ch5 / 3;
    int c = ch5 - g*3;
    int dh = (g==0) ? 0 : ((g & 1) ? 8 : -8);
    int dw = (g==0) ? 0 : ((g <= 2) ? 8 : -8);
    int ii = ph*16 + p + dh;
    int jj = pw*16 + q + dw;
    float v = 0.f;
    if ((unsigned)ii < IMG && (unsigned)jj < IMG)
      v = images[((b*IMG + ii)*IMG + jj)*3 + c];
    s += v; s2 += v*v;
    patches_out[(size_t)pid*PD + d] = v;
  }
  #pragma unroll
  for (int o = 32; o > 0; o >>= 1) { s += __shfl_xor(s, o); s2 += __shfl_xor(s2, o); }
  __shared__ float red[8];
  int w = t >> 6;
  if ((t & 63) == 0) { red[w*2] = s; red[w*2+1] = s2; }
  __syncthreads();
  if (t == 0) {
    float S  = red[0]+red[2]+red[4]+red[6];
    float S2 = red[1]+red[3]+red[5]+red[7];
    float mean = S * (1.f/PD);
    float var  = S2 * (1.f/PD) - mean*mean;
    mr[pid] = make_float2(mean, rsqrtf(var + 1e-6f));
  }
}

__global__ __launch_bounds__(256) void wtrans_kernel(
    const float* __restrict__ W, unsigned short* __restrict__ Wt) {
  __shared__ float tile[32][33];
  const int bx = blockIdx.x;
  const int by = blockIdx.y;
  const int tx = threadIdx.x & 31;
  const int ty = threadIdx.x >> 5;
  #pragma unroll
  for (int r = 0; r < 4; ++r)
    tile[ty + r*8][tx] = W[(by*32 + ty + r*8)*PROJ + bx*32 + tx];
  __syncthreads();
  #pragma unroll
  for (int r = 0; r < 4; ++r)
    Wt[(size_t)(bx*32 + ty + r*8)*PD + by*32 + tx] = f2bf(tile[tx][ty + r*8]);
}

__global__ __launch_bounds__(256) void gemm_kernel(
    const float* __restrict__ patches, const float2* __restrict__ mr,
    const float* __restrict__ gamma, const float* __restrict__ beta,
    const unsigned short* __restrict__ Wt, const float* __restrict__ bias,
    float* __restrict__ tokens) {
  __shared__ unsigned short Alds[128][40];
  const int bn = blockIdx.x;
  const int bm = blockIdx.y;
  const int t = threadIdx.x;
  const int l = t & 63;
  const int w = t >> 6;
  const int wr = w >> 1, wc = w & 1;
  const int m0 = bm * 128, n0 = bn * 128;
  const int lrow = l & 15, lk = l >> 4;
  const unsigned short* bp[4];
  #pragma unroll
  for (int fc = 0; fc < 4; ++fc)
    bp[fc] = Wt + (size_t)(n0 + wc*64 + fc*16 + lrow) * PD + lk*8;
  const int srow = t >> 3;
  const int skq  = (t & 7) * 4;
  f32x4 acc[4][4];
  #pragma unroll
  for (int i = 0; i < 4; ++i)
    #pragma unroll
    for (int j = 0; j < 4; ++j) acc[i][j] = f32x4{0.f, 0.f, 0.f, 0.f};
  bf16x8 bfrag[4], bnext[4];
  #pragma unroll
  for (int fc = 0; fc < 4; ++fc) bfrag[fc] = *reinterpret_cast<const bf16x8*>(bp[fc]);
  for (int kt = 0; kt < KT; ++kt) {
    const int k0 = kt * 32;
    #pragma unroll
    for (int pass = 0; pass < 4; ++pass) {
      int row = pass*32 + srow;
      int m = m0 + row;
      float2 mrv = mr[m];
      const float4 v  = *reinterpret_cast<const float4*>(patches + (size_t)m*PD + k0 + skq);
      const float4 gv = *reinterpret_cast<const float4*>(gamma + k0 + skq);
      const float4 bv = *reinterpret_cast<const float4*>(beta  + k0 + skq);
      ushort4 o;
      o.x = f2bf((v.x - mrv.x)*mrv.y*gv.x + bv.x);
      o.y = f2bf((v.y - mrv.x)*mrv.y*gv.y + bv.y);
      o.z = f2bf((v.z - mrv.x)*mrv.y*gv.z + bv.z);
      o.w = f2bf((v.w - mrv.x)*mrv.y*gv.w + bv.w);
      *reinterpret_cast<ushort4*>(&Alds[row][skq]) = o;
    }
    if (kt < KT-1) {
      #pragma unroll
      for (int fc = 0; fc < 4; ++fc)
        bnext[fc] = *reinterpret_cast<const bf16x8*>(bp[fc] + k0 + 32);
    }
    __syncthreads();
    bf16x8 afrag[4];
    #pragma unroll
    for (int fr = 0; fr < 4; ++fr)
      afrag[fr] = *reinterpret_cast<const bf16x8*>(&Alds[wr*64 + fr*16 + lrow][lk*8]);
    #pragma unroll
    for (int fr = 0; fr < 4; ++fr)
      #pragma unroll
      for (int fc = 0; fc < 4; ++fc)
        acc[fr][fc] = __builtin_amdgcn_mfma_f32_16x16x32_bf16(
            afrag[fr], bfrag[fc], acc[fr][fc], 0, 0, 0);
    __syncthreads();
    #pragma unroll
    for (int fc = 0; fc < 4; ++fc) bfrag[fc] = bnext[fc];
  }
  #pragma unroll
  for (int fr = 0; fr < 4; ++fr) {
    int mrow = m0 + wr*64 + fr*16 + lk*4;
    #pragma unroll
    for (int fc = 0; fc < 4; ++fc) {
      int col = n0 + wc*64 + fc*16 + lrow;
      float bb = bias[col];
      #pragma unroll
      for (int i = 0; i < 4; ++i)
        tokens[(size_t)(mrow + i)*PROJ + col] = acc[fr][fc][i] + bb;
    }
  }
}

// ============== launcher ==============

extern "C" void kernel_launch(void* const* d_in, const int* in_sizes, int n_in,
                              void* d_out, int out_size, void* d_ws, size_t ws_size,
                              hipStream_t stream) {
  const float* images = (const float*)d_in[0];
  const float* gamma  = (const float*)d_in[1];
  const float* beta   = (const float*)d_in[2];
  const float* W      = (const float*)d_in[3];
  const float* bias   = (const float*)d_in[4];
  float* tokens  = (float*)d_out;
  float* patches = (float*)d_out + TOK_SIZE;

  const size_t WS_A_OFF = 6u << 20;                               // 6 MiB
  const size_t need = WS_A_OFF + (size_t)MT*KT*TILE_BYTES;        // ~98 MiB

  if (ws_size >= need) {
    char* Bws = (char*)d_ws;
    char* Aws = (char*)d_ws + WS_A_OFF;
    prep4_kernel<<<1024, 512, 0, stream>>>(images, gamma, beta, patches, Aws);
    wtrans2_kernel<<<dim3(24, KT), 256, 0, stream>>>(W, Bws);
    gemm5_kernel<<<MT*NT, 256, 0, stream>>>(Aws, Bws, bias, tokens);
  } else {
    float2* mrp = (float2*)d_ws;
    unsigned short* Wt = (unsigned short*)((char*)d_ws + (1 << 20));
    prep_kernel<<<M_TOT, 256, 0, stream>>>(images, patches, mrp);
    wtrans_kernel<<<dim3(24, KT), 256, 0, stream>>>(W, Wt);
    gemm_kernel<<<dim3(NT, MT), 256, 0, stream>>>(patches, mrp, gamma, beta, Wt, bias, tokens);
  }
}